// Round 3
// baseline (402.811 us; speedup 1.0000x reference)
//
#include <hip/hip_runtime.h>
#include <hip/hip_bf16.h>
#include <math.h>

#define NTOK 16384
#define HDIM 1024
#define DSZ 32
#define DGZ 32
#define FMZ 64
#define NEXP 4
#define FFZ 2048

typedef __attribute__((ext_vector_type(4))) float f32x4;
typedef __attribute__((ext_vector_type(8))) short bf16x8;

__device__ __forceinline__ unsigned short f2bf(float f){
    union { float f; unsigned int u; } v; v.f = f;
    unsigned int r = (v.u + 0x7FFFu + ((v.u >> 16) & 1u)) >> 16;
    return (unsigned short)r;
}
__device__ __forceinline__ float gelu_f(float x){
    return 0.5f * x * (1.0f + erff(x * 0.70710678118654752440f));
}
__device__ __forceinline__ void gld_lds16(const void* g, void* s){
    __builtin_amdgcn_global_load_lds((const __attribute__((address_space(1))) unsigned int*)g,
                                     (__attribute__((address_space(3))) unsigned int*)s, 16, 0, 0);
}

// ---------------- kernel 1: per-token LN stats + h -> bf16 ----------------
__global__ __launch_bounds__(256) void k_stats(const float* __restrict__ h,
        unsigned short* __restrict__ hbf, float* __restrict__ mu_g, float* __restrict__ rs_g){
    int tid = threadIdx.x;
    int wv = tid >> 6, l = tid & 63;
    int tok = blockIdx.x * 4 + wv;
    const float4* hp = (const float4*)(h + (size_t)tok * HDIM);
    ushort4* op = (ushort4*)(hbf + (size_t)tok * HDIM);
    float s = 0.f, s2 = 0.f;
    #pragma unroll
    for (int p = 0; p < 4; ++p){
        float4 v = hp[p * 64 + l];
        s  += v.x + v.y + v.z + v.w;
        s2 += v.x*v.x + v.y*v.y + v.z*v.z + v.w*v.w;
        ushort4 o; o.x = f2bf(v.x); o.y = f2bf(v.y); o.z = f2bf(v.z); o.w = f2bf(v.w);
        op[p * 64 + l] = o;
    }
    #pragma unroll
    for (int off = 32; off >= 1; off >>= 1){
        s  += __shfl_xor(s,  off, 64);
        s2 += __shfl_xor(s2, off, 64);
    }
    if (l == 0){
        float mu = s * (1.0f / HDIM);
        float var = s2 * (1.0f / HDIM) - mu * mu;
        var = fmaxf(var, 0.f);
        mu_g[tok] = mu;
        rs_g[tok] = 1.0f / sqrtf(var + 1e-5f);
    }
}

// ---------------- kernel 2: transpose + fp32->bf16 (weights, per expert) ----------------
__global__ __launch_bounds__(256) void k_transpose_bf(const float* __restrict__ in,
        unsigned short* __restrict__ out, int R, int C){
    __shared__ float tile[32][33];
    size_t mat = (size_t)blockIdx.z * R * C;
    int bx = blockIdx.x * 32;   // col base
    int by = blockIdx.y * 32;   // row base
    int x = threadIdx.x, y = threadIdx.y;
    const float* ip = in + mat;
    unsigned short* op = out + mat;
    #pragma unroll
    for (int i = 0; i < 32; i += 8)
        tile[y + i][x] = ip[(size_t)(by + y + i) * C + (bx + x)];
    __syncthreads();
    #pragma unroll
    for (int i = 0; i < 32; i += 8)
        op[(size_t)(bx + y + i) * R + (by + x)] = f2bf(tile[x][y + i]);
}

// ---------------- kernel 3: fused fp32 routing (unchanged, verified) ----------------
__global__ __launch_bounds__(256) void k_route(
    const float* __restrict__ h, const float* __restrict__ tok_emb,
    const float* __restrict__ ln_g, const float* __restrict__ ln_b,
    const float* __restrict__ Wg, const float* __restrict__ bg,
    const float* __restrict__ Wf, const float* __restrict__ bfv,
    const float* __restrict__ Wr, const float* __restrict__ br,
    const float* __restrict__ mu_g, const float* __restrict__ rs_g,
    float* __restrict__ tprob, int* __restrict__ list, int* __restrict__ cnt,
    float* __restrict__ imp_part)
{
    __shared__ __align__(16) char smem[62208];
    float* lgs  = (float*)(smem);                      // [1024]
    float* lbs  = (float*)(smem + 4096);               // [1024]
    float (*hsT)[64]  = (float(*)[64])(smem + 8192);   // [64 k][64 tok]
    float (*wgs)[32]  = (float(*)[32])(smem + 24576);  // [64 k][32 c]
    float (*gacc)[32] = (float(*)[32])(smem + 32768);  // [64 tok][32 c]
    float* mus = (float*)(smem + 40960);               // [64]
    float* rss = (float*)(smem + 41216);               // [64]
    float (*wrs)[4]     = (float(*)[4])(smem + 41472); // [64][4]
    float (*logit_s)[5] = (float(*)[5])(smem + 42496);
    float (*prob_s)[5]  = (float(*)[5])(smem + 43776);
    int* lcnt  = (int*)(smem + 45056);
    int* lbase = (int*)(smem + 45072);
    float (*agT)[64] = (float(*)[64])(smem);           // [64 j][64 tok]
    float (*wfs)[64] = (float(*)[64])(smem + 16384);   // [64 k][64 f]
    float (*uT)[64]  = (float(*)[64])(smem + 45824);   // [64 f][64 tok]

    int tid = threadIdx.x;
    int t0 = blockIdx.x * 64;

    ((float4*)lgs)[tid] = ((const float4*)ln_g)[tid];
    ((float4*)lbs)[tid] = ((const float4*)ln_b)[tid];
    if (tid < 64){ mus[tid] = mu_g[t0 + tid]; rss[tid] = rs_g[t0 + tid]; }
    if (tid < 64) ((float4*)wrs)[tid] = ((const float4*)Wr)[tid];
    if (tid < 4) lcnt[tid] = 0;
    __syncthreads();

    int l = tid & 63, w = tid >> 6;
    int tg = l & 7, cg = l >> 3, q = w;
    float g_[8][4];
    #pragma unroll
    for (int i=0;i<8;++i){ g_[i][0]=0.f; g_[i][1]=0.f; g_[i][2]=0.f; g_[i][3]=0.f; }
    int tokrow = tid >> 2;
    float m_ = mus[tokrow], r_ = rss[tokrow];
    const float* hrow = h + (size_t)(t0 + tokrow) * HDIM;

    for (int k0 = 0; k0 < HDIM; k0 += 64){
        #pragma unroll
        for (int p = 0; p < 4; ++p){
            int f4 = (tid & 3) + 4 * p;
            float4 v = ((const float4*)(hrow + k0))[f4];
            int c = f4 * 4;
            hsT[c+0][tokrow] = (v.x - m_) * r_ * lgs[k0+c+0] + lbs[k0+c+0];
            hsT[c+1][tokrow] = (v.y - m_) * r_ * lgs[k0+c+1] + lbs[k0+c+1];
            hsT[c+2][tokrow] = (v.z - m_) * r_ * lgs[k0+c+2] + lbs[k0+c+2];
            hsT[c+3][tokrow] = (v.w - m_) * r_ * lgs[k0+c+3] + lbs[k0+c+3];
        }
        {
            int wgrow = tid >> 2;
            #pragma unroll
            for (int p = 0; p < 2; ++p){
                int f4 = (tid & 3) + 4 * p;
                ((float4*)wgs[wgrow])[f4] = ((const float4*)(Wg + (size_t)(k0 + wgrow) * DGZ))[f4];
            }
        }
        __syncthreads();
        #pragma unroll
        for (int kk16 = 0; kk16 < 16; ++kk16){
            int kk = q * 16 + kk16;
            float4 a0 = ((float4*)hsT[kk])[tg*2];
            float4 a1 = ((float4*)hsT[kk])[tg*2+1];
            float4 wv = ((float4*)wgs[kk])[cg];
            float av[8] = {a0.x,a0.y,a0.z,a0.w,a1.x,a1.y,a1.z,a1.w};
            float wj[4] = {wv.x,wv.y,wv.z,wv.w};
            #pragma unroll
            for (int i=0;i<8;++i){
                g_[i][0] += av[i]*wj[0]; g_[i][1] += av[i]*wj[1];
                g_[i][2] += av[i]*wj[2]; g_[i][3] += av[i]*wj[3];
            }
        }
        __syncthreads();
    }
    for (int qq = 0; qq < 4; ++qq){
        if (w == qq){
            #pragma unroll
            for (int i=0;i<8;++i){
                int tok = tg*8+i;
                #pragma unroll
                for (int j=0;j<4;++j){
                    int c = cg*4+j;
                    if (qq == 0) gacc[tok][c] = g_[i][j];
                    else gacc[tok][c] += g_[i][j];
                }
            }
        }
        __syncthreads();
    }
    {
        int tokr = tid >> 2;
        #pragma unroll
        for (int p = 0; p < 2; ++p){
            int f4 = (tid & 3) + 4*p;
            float4 v = ((const float4*)(tok_emb + (size_t)(t0 + tokr) * DSZ))[f4];
            int j = f4 * 4;
            agT[j+0][tokr] = v.x; agT[j+1][tokr] = v.y;
            agT[j+2][tokr] = v.z; agT[j+3][tokr] = v.w;
        }
        int c = tid & 31, tok8 = (tid >> 5) * 8;
        float bgc = bg[c];
        #pragma unroll
        for (int i=0;i<8;++i){
            int tok = tok8 + i;
            agT[32 + c][tok] = gelu_f(gacc[tok][c] + bgc);
        }
        int row = tid >> 2;
        #pragma unroll
        for (int p = 0; p < 4; ++p){
            int f4 = (tid & 3) + 4*p;
            ((float4*)wfs[row])[f4] = ((const float4*)(Wf + (size_t)row * FMZ))[f4];
        }
    }
    __syncthreads();
    {
        int tok = tid & 63, fq = tid >> 6;
        float u_[16];
        #pragma unroll
        for (int i=0;i<16;++i) u_[i]=0.f;
        for (int j = 0; j < 64; ++j){
            float a = agT[j][tok];
            float wv[16];
            *(float4*)&wv[0]  = ((float4*)wfs[j])[fq*4+0];
            *(float4*)&wv[4]  = ((float4*)wfs[j])[fq*4+1];
            *(float4*)&wv[8]  = ((float4*)wfs[j])[fq*4+2];
            *(float4*)&wv[12] = ((float4*)wfs[j])[fq*4+3];
            #pragma unroll
            for (int i=0;i<16;++i) u_[i] += a * wv[i];
        }
        #pragma unroll
        for (int i=0;i<16;++i){
            int f = fq*16+i;
            uT[f][tok] = gelu_f(u_[i] + bfv[f]);
        }
    }
    __syncthreads();
    {
        int tok = tid & 63, e = tid >> 6;
        float lt = 0.f;
        #pragma unroll 8
        for (int f = 0; f < 64; ++f) lt += uT[f][tok] * wrs[f][e];
        logit_s[tok][e] = lt + br[e];
    }
    __syncthreads();
    int my_e = 0, my_pos = 0;
    if (tid < 64){
        int tok = tid;
        float l0 = logit_s[tok][0], l1 = logit_s[tok][1];
        float l2 = logit_s[tok][2], l3 = logit_s[tok][3];
        float mx = fmaxf(fmaxf(l0,l1), fmaxf(l2,l3));
        float p0 = expf(l0-mx), p1 = expf(l1-mx), p2 = expf(l2-mx), p3 = expf(l3-mx);
        float inv = 1.0f / (p0+p1+p2+p3);
        int be = 0; float bp = p0;
        if (p1 > bp){ bp = p1; be = 1; }
        if (p2 > bp){ bp = p2; be = 2; }
        if (p3 > bp){ bp = p3; be = 3; }
        tprob[t0 + tok] = bp * inv;
        prob_s[tok][0] = p0*inv; prob_s[tok][1] = p1*inv;
        prob_s[tok][2] = p2*inv; prob_s[tok][3] = p3*inv;
        my_e = be;
        my_pos = atomicAdd(&lcnt[be], 1);
    }
    __syncthreads();
    if (tid < 4) lbase[tid] = atomicAdd(&cnt[tid], lcnt[tid]);
    __syncthreads();
    if (tid < 64) list[my_e * NTOK + lbase[my_e] + my_pos] = t0 + tid;
    if (tid < 4){
        float s = 0.f;
        for (int t = 0; t < 64; ++t) s += prob_s[t][tid];
        imp_part[blockIdx.x * 4 + tid] = s;
    }
}

// ---------------- grouped expert GEMM: 256x256 tile, 8-phase counted-vmcnt ----------------
// 512 threads = 8 waves (2M x 4N). BK=64 split into two 32-k halves.
// LDS 128KiB: A: [2 dbuf][2 khalf][256 rows][32 k] (16KB halves), B same at +64KiB.
// Swizzle (T2): within a half, row stride 64B, 4x16B chunks: LDS[r][c] = G[r][c ^ ((r>>1)&3)]
//   write side: pre-swizzled GLOBAL source chunk (gld_lds dest stays linear);
//   read side: chunk = (l>>4) ^ ((l&15)>>1 & 3)  -> 2-way banks (free).
// Schedule per K-tile t (4 phases = m-half x k-half quadrants of 16 MFMA):
//   P0 (mh0,kc0): read a+b(kc0); stage A-kh1(t+1)          -> barrier, MFMA, fence(lgkm), barrier
//   P1 (mh1,kc0): read a;        stage B-kh1(t+1)          -> barrier, MFMA, fence(vmcnt(8)+lgkm), barrier
//   P2 (mh0,kc1): read a+b(kc1); stage A-kh0(t+2)          -> barrier, MFMA, fence(lgkm), barrier
//   P3 (mh1,kc1): read a;        stage B-kh0(t+2)          -> barrier, MFMA, fence(vmcnt(8)+lgkm), barrier
// Invariant: after each vmcnt(8), exactly 4 half-tiles (8 loads) in flight; the retired
// prefix is exactly the data the next quadrant pair reads. Never vmcnt(0) in the loop (T4).
template<int KTD, int NT, bool PH1>
__global__ __launch_bounds__(512, 2) void k_gemm256(
    const unsigned short* __restrict__ Abase,
    const unsigned short* __restrict__ Bbase,
    const int* __restrict__ list, const int* __restrict__ cnt_g,
    const float* __restrict__ bias,
    unsigned short* __restrict__ A1out,
    const float* __restrict__ hres,
    const float* __restrict__ tprob,
    float* __restrict__ outp)
{
    constexpr int NKT = KTD / 64;
    constexpr int NKTm1 = NKT - 1;
    __shared__ __align__(16) char lds[131072];
    int e = blockIdx.z;
    int cnt = cnt_g[e];
    int m0 = blockIdx.y * 256;
    if (m0 >= cnt) return;
    int n0 = blockIdx.x * 256;
    int tid = threadIdx.x, w = tid >> 6, l = tid & 63;
    int wr = w >> 2, wc = w & 3;

    // staging mapping: thread -> (row = tid>>2 [+128 on 2nd load], src chunk jsrc)
    int srow = tid >> 2;
    int jsrc = (tid & 3) ^ ((tid >> 3) & 3);
    int g0 = m0 + srow;       if (g0 > cnt-1) g0 = cnt-1;
    int g1 = m0 + 128 + srow; if (g1 > cnt-1) g1 = cnt-1;
    int tok0 = list[e * NTOK + g0], tok1 = list[e * NTOK + g1];
    const unsigned short* Asrc0 = Abase + (size_t)tok0 * KTD + jsrc * 8;
    const unsigned short* Asrc1 = Abase + (size_t)tok1 * KTD + jsrc * 8;
    const unsigned short* Bsrc0 = Bbase + ((size_t)e * NT + n0 + srow) * KTD + jsrc * 8;
    const unsigned short* Bsrc1 = Bsrc0 + (size_t)128 * KTD;

    // fragment read offsets (swizzled, 2-way banks)
    int lane_off = (l & 15) * 64 + (((l >> 4) ^ (((l & 15) >> 1) & 3)) * 16);
    int aoff = wr * 8192 + lane_off;            // + mh*4096 + m*1024
    int boff = 65536 + wc * 4096 + lane_off;    // + n*1024

#define STAGE_A(KIDX, KC, DOF) do { \
    int kq_ = (KIDX); if (kq_ > NKTm1) kq_ = NKTm1; \
    size_t so_ = (size_t)kq_ * 64 + (KC) * 32; \
    gld_lds16(Asrc0 + so_, lds + (DOF) + (KC) * 16384 + tid * 16); \
    gld_lds16(Asrc1 + so_, lds + (DOF) + (KC) * 16384 + 8192 + tid * 16); } while(0)
#define STAGE_B(KIDX, KC, DOF) do { \
    int kq_ = (KIDX); if (kq_ > NKTm1) kq_ = NKTm1; \
    size_t so_ = (size_t)kq_ * 64 + (KC) * 32; \
    gld_lds16(Bsrc0 + so_, lds + 65536 + (DOF) + (KC) * 16384 + tid * 16); \
    gld_lds16(Bsrc1 + so_, lds + 65536 + (DOF) + (KC) * 16384 + 8192 + tid * 16); } while(0)
#define AFRAG(MH, KC, M) (*(const bf16x8*)(lds + dof + (KC) * 16384 + aoff + (MH) * 4096 + (M) * 1024))
#define BFRAG(KC, N)     (*(const bf16x8*)(lds + dof + (KC) * 16384 + boff + (N) * 1024))
#define MM16(MB, A0, A1, A2, A3) do { \
    acc[(MB)+0][0] = __builtin_amdgcn_mfma_f32_16x16x32_bf16(A0, b0, acc[(MB)+0][0], 0,0,0); \
    acc[(MB)+1][0] = __builtin_amdgcn_mfma_f32_16x16x32_bf16(A1, b0, acc[(MB)+1][0], 0,0,0); \
    acc[(MB)+2][0] = __builtin_amdgcn_mfma_f32_16x16x32_bf16(A2, b0, acc[(MB)+2][0], 0,0,0); \
    acc[(MB)+3][0] = __builtin_amdgcn_mfma_f32_16x16x32_bf16(A3, b0, acc[(MB)+3][0], 0,0,0); \
    acc[(MB)+0][1] = __builtin_amdgcn_mfma_f32_16x16x32_bf16(A0, b1, acc[(MB)+0][1], 0,0,0); \
    acc[(MB)+1][1] = __builtin_amdgcn_mfma_f32_16x16x32_bf16(A1, b1, acc[(MB)+1][1], 0,0,0); \
    acc[(MB)+2][1] = __builtin_amdgcn_mfma_f32_16x16x32_bf16(A2, b1, acc[(MB)+2][1], 0,0,0); \
    acc[(MB)+3][1] = __builtin_amdgcn_mfma_f32_16x16x32_bf16(A3, b1, acc[(MB)+3][1], 0,0,0); \
    acc[(MB)+0][2] = __builtin_amdgcn_mfma_f32_16x16x32_bf16(A0, b2, acc[(MB)+0][2], 0,0,0); \
    acc[(MB)+1][2] = __builtin_amdgcn_mfma_f32_16x16x32_bf16(A1, b2, acc[(MB)+1][2], 0,0,0); \
    acc[(MB)+2][2] = __builtin_amdgcn_mfma_f32_16x16x32_bf16(A2, b2, acc[(MB)+2][2], 0,0,0); \
    acc[(MB)+3][2] = __builtin_amdgcn_mfma_f32_16x16x32_bf16(A3, b2, acc[(MB)+3][2], 0,0,0); \
    acc[(MB)+0][3] = __builtin_amdgcn_mfma_f32_16x16x32_bf16(A0, b3, acc[(MB)+0][3], 0,0,0); \
    acc[(MB)+1][3] = __builtin_amdgcn_mfma_f32_16x16x32_bf16(A1, b3, acc[(MB)+1][3], 0,0,0); \
    acc[(MB)+2][3] = __builtin_amdgcn_mfma_f32_16x16x32_bf16(A2, b3, acc[(MB)+2][3], 0,0,0); \
    acc[(MB)+3][3] = __builtin_amdgcn_mfma_f32_16x16x32_bf16(A3, b3, acc[(MB)+3][3], 0,0,0); } while(0)
#define FENCE_LG   do { asm volatile("s_waitcnt lgkmcnt(0)" ::: "memory"); \
    __builtin_amdgcn_sched_barrier(0); __builtin_amdgcn_s_barrier(); } while(0)
#define FENCE_VM   do { asm volatile("s_waitcnt vmcnt(8) lgkmcnt(0)" ::: "memory"); \
    __builtin_amdgcn_sched_barrier(0); __builtin_amdgcn_s_barrier(); } while(0)

    f32x4 acc[8][4] = {};
    bf16x8 b0, b1, b2, b3;

    // prologue: stage kh0(0), kh1(0), kh0(1); retire kh0(0) -> invariant holds at t=0
    STAGE_A(0, 0, 0);     STAGE_B(0, 0, 0);
    STAGE_A(0, 1, 0);     STAGE_B(0, 1, 0);
    STAGE_A(1, 0, 32768); STAGE_B(1, 0, 32768);
    asm volatile("s_waitcnt vmcnt(8)" ::: "memory");
    __builtin_amdgcn_sched_barrier(0);
    __builtin_amdgcn_s_barrier();

    int dof = 0;
    for (int kt = 0; kt < NKT; ++kt, dof ^= 32768){
        const int dofN = dof ^ 32768;
        {   // P0: (mh0, kc0)
            bf16x8 a0 = AFRAG(0,0,0), a1 = AFRAG(0,0,1), a2 = AFRAG(0,0,2), a3 = AFRAG(0,0,3);
            b0 = BFRAG(0,0); b1 = BFRAG(0,1); b2 = BFRAG(0,2); b3 = BFRAG(0,3);
            STAGE_A(kt + 1, 1, dofN);
            __builtin_amdgcn_s_barrier();
            __builtin_amdgcn_s_setprio(1);
            MM16(0, a0, a1, a2, a3);
            __builtin_amdgcn_s_setprio(0);
            FENCE_LG;
        }
        {   // P1: (mh1, kc0)
            bf16x8 a0 = AFRAG(1,0,0), a1 = AFRAG(1,0,1), a2 = AFRAG(1,0,2), a3 = AFRAG(1,0,3);
            STAGE_B(kt + 1, 1, dofN);
            __builtin_amdgcn_s_barrier();
            __builtin_amdgcn_s_setprio(1);
            MM16(4, a0, a1, a2, a3);
            __builtin_amdgcn_s_setprio(0);
            FENCE_VM;
        }
        {   // P2: (mh0, kc1)
            bf16x8 a0 = AFRAG(0,1,0), a1 = AFRAG(0,1,1), a2 = AFRAG(0,1,2), a3 = AFRAG(0,1,3);
            b0 = BFRAG(1,0); b1 = BFRAG(1,1); b2 = BFRAG(1,2); b3 = BFRAG(1,3);
            STAGE_A(kt + 2, 0, dof);
            __builtin_amdgcn_s_barrier();
            __builtin_amdgcn_s_setprio(1);
            MM16(0, a0, a1, a2, a3);
            __builtin_amdgcn_s_setprio(0);
            FENCE_LG;
        }
        {   // P3: (mh1, kc1)
            bf16x8 a0 = AFRAG(1,1,0), a1 = AFRAG(1,1,1), a2 = AFRAG(1,1,2), a3 = AFRAG(1,1,3);
            STAGE_B(kt + 2, 0, dof);
            __builtin_amdgcn_s_barrier();
            __builtin_amdgcn_s_setprio(1);
            MM16(4, a0, a1, a2, a3);
            __builtin_amdgcn_s_setprio(0);
            FENCE_VM;
        }
    }

    // epilogue: C/D layout col = lane&15 (+16*n group), row = (lane>>4)*4 + reg (+16*M)
    #pragma unroll
    for (int M = 0; M < 8; ++M){
        #pragma unroll
        for (int r = 0; r < 4; ++r){
            int row = wr * 128 + M * 16 + (l >> 4) * 4 + r;
            int g = m0 + row;
            if (g < cnt){
                int tok = list[e * NTOK + g];
                if (PH1){
                    #pragma unroll
                    for (int n = 0; n < 4; ++n){
                        int col = n0 + wc * 64 + n * 16 + (l & 15);
                        float v = acc[M][n][r] + bias[e * NT + col];
                        A1out[(size_t)tok * FFZ + col] = f2bf(gelu_f(v));
                    }
                } else {
                    float sc = 0.5f * tprob[tok];
                    #pragma unroll
                    for (int n = 0; n < 4; ++n){
                        int col = n0 + wc * 64 + n * 16 + (l & 15);
                        float v = acc[M][n][r] + bias[e * NT + col];
                        size_t o = (size_t)tok * HDIM + col;
                        outp[o] = hres[o] + sc * v;
                    }
                }
            }
        }
    }
#undef STAGE_A
#undef STAGE_B
#undef AFRAG
#undef BFRAG
#undef MM16
#undef FENCE_LG
#undef FENCE_VM
}

// ---------------- final: lb_loss ----------------
__global__ void k_final(const float* __restrict__ imp_part, const int* __restrict__ cnt,
                        float* __restrict__ outp){
    __shared__ float imp_s[4];
    int tid = threadIdx.x;
    if (tid < 4){
        float s = 0.f;
        for (int b = 0; b < 256; ++b) s += imp_part[b*4 + tid];
        imp_s[tid] = s;
    }
    __syncthreads();
    if (tid == 0){
        float lb = 0.f;
        #pragma unroll
        for (int e = 0; e < 4; ++e) lb += imp_s[e] * (float)cnt[e];
        outp[(size_t)NTOK * HDIM] = (float)NEXP * lb / ((float)NTOK * (float)NTOK + 1e-8f);
    }
}

extern "C" void kernel_launch(void* const* d_in, const int* in_sizes, int n_in,
                              void* d_out, int out_size, void* d_ws, size_t ws_size,
                              hipStream_t stream){
    const float* h       = (const float*)d_in[0];
    const float* tok_emb = (const float*)d_in[1];
    const float* ln_g = (const float*)d_in[3];
    const float* ln_b = (const float*)d_in[4];
    const float* Wg   = (const float*)d_in[5];
    const float* bg   = (const float*)d_in[6];
    const float* Wf   = (const float*)d_in[7];
    const float* bfv  = (const float*)d_in[8];
    const float* Wr   = (const float*)d_in[9];
    const float* br   = (const float*)d_in[10];
    const float* W1   = (const float*)d_in[11];
    const float* b1   = (const float*)d_in[12];
    const float* W2   = (const float*)d_in[13];
    const float* b2   = (const float*)d_in[14];
    float* outp = (float*)d_out;
    char* ws = (char*)d_ws;

    unsigned short* h_bf = (unsigned short*)(ws);               // 33554432 B
    unsigned short* W1T  = (unsigned short*)(ws + 33554432);    // 16777216 B  [E][FFZ][HDIM]
    unsigned short* W2T  = (unsigned short*)(ws + 50331648);    // 16777216 B  [E][HDIM][FFZ]
    unsigned short* A1   = (unsigned short*)(ws + 67108864);    // 67108864 B  [NTOK][FFZ]
    float* mu_g  = (float*)(ws + 134217728);
    float* rs_g  = (float*)(ws + 134283264);
    float* tprob = (float*)(ws + 134348800);
    int*   list  = (int*)(ws + 134414336);                      // [E][NTOK]
    int*   cnt   = (int*)(ws + 134676480);                      // [E]
    float* imp   = (float*)(ws + 134676736);                    // [256][E]

    hipMemsetAsync(cnt, 0, NEXP * sizeof(int), stream);
    k_stats<<<NTOK/4, 256, 0, stream>>>(h, h_bf, mu_g, rs_g);
    k_transpose_bf<<<dim3(FFZ/32, HDIM/32, NEXP), dim3(32,8), 0, stream>>>(W1, W1T, HDIM, FFZ);
    k_transpose_bf<<<dim3(HDIM/32, FFZ/32, NEXP), dim3(32,8), 0, stream>>>(W2, W2T, FFZ, HDIM);
    k_route<<<NTOK/64, 256, 0, stream>>>(h, tok_emb, ln_g, ln_b, Wg, bg, Wf, bfv, Wr, br,
                                         mu_g, rs_g, tprob, list, cnt, imp);
    k_gemm256<HDIM, FFZ, true><<<dim3(FFZ/256, NTOK/256, NEXP), 512, 0, stream>>>(
        h_bf, W1T, list, cnt, b1, A1, nullptr, nullptr, nullptr);
    k_gemm256<FFZ, HDIM, false><<<dim3(HDIM/256, NTOK/256, NEXP), 512, 0, stream>>>(
        A1, W2T, list, cnt, b2, nullptr, h, tprob, outp);
    k_final<<<1, 64, 0, stream>>>(imp, cnt, outp);
}

// Round 4
// 382.411 us; speedup vs baseline: 1.0533x; 1.0533x over previous
//
#include <hip/hip_runtime.h>
#include <hip/hip_bf16.h>
#include <math.h>

#define NTOK 16384
#define HDIM 1024
#define DSZ 32
#define DGZ 32
#define FMZ 64
#define NEXP 4
#define FFZ 2048

typedef __attribute__((ext_vector_type(4))) float f32x4;
typedef __attribute__((ext_vector_type(8))) short bf16x8;

__device__ __forceinline__ unsigned short f2bf(float f){
    union { float f; unsigned int u; } v; v.f = f;
    unsigned int r = (v.u + 0x7FFFu + ((v.u >> 16) & 1u)) >> 16;
    return (unsigned short)r;
}
__device__ __forceinline__ float gelu_f(float x){
    return 0.5f * x * (1.0f + erff(x * 0.70710678118654752440f));
}
__device__ __forceinline__ void gld_lds16(const void* g, void* s){
    __builtin_amdgcn_global_load_lds((const __attribute__((address_space(1))) unsigned int*)g,
                                     (__attribute__((address_space(3))) unsigned int*)s, 16, 0, 0);
}

// ---------------- kernel 1: per-token LN stats + h -> bf16 ----------------
__global__ __launch_bounds__(256) void k_stats(const float* __restrict__ h,
        unsigned short* __restrict__ hbf, float* __restrict__ mu_g, float* __restrict__ rs_g){
    int tid = threadIdx.x;
    int wv = tid >> 6, l = tid & 63;
    int tok = blockIdx.x * 4 + wv;
    const float4* hp = (const float4*)(h + (size_t)tok * HDIM);
    ushort4* op = (ushort4*)(hbf + (size_t)tok * HDIM);
    float s = 0.f, s2 = 0.f;
    #pragma unroll
    for (int p = 0; p < 4; ++p){
        float4 v = hp[p * 64 + l];
        s  += v.x + v.y + v.z + v.w;
        s2 += v.x*v.x + v.y*v.y + v.z*v.z + v.w*v.w;
        ushort4 o; o.x = f2bf(v.x); o.y = f2bf(v.y); o.z = f2bf(v.z); o.w = f2bf(v.w);
        op[p * 64 + l] = o;
    }
    #pragma unroll
    for (int off = 32; off >= 1; off >>= 1){
        s  += __shfl_xor(s,  off, 64);
        s2 += __shfl_xor(s2, off, 64);
    }
    if (l == 0){
        float mu = s * (1.0f / HDIM);
        float var = s2 * (1.0f / HDIM) - mu * mu;
        var = fmaxf(var, 0.f);
        mu_g[tok] = mu;
        rs_g[tok] = 1.0f / sqrtf(var + 1e-5f);
    }
}

// ---------------- kernel 2: transpose + fp32->bf16 (weights, per expert) ----------------
__global__ __launch_bounds__(256) void k_transpose_bf(const float* __restrict__ in,
        unsigned short* __restrict__ out, int R, int C){
    __shared__ float tile[32][33];
    size_t mat = (size_t)blockIdx.z * R * C;
    int bx = blockIdx.x * 32;   // col base
    int by = blockIdx.y * 32;   // row base
    int x = threadIdx.x, y = threadIdx.y;
    const float* ip = in + mat;
    unsigned short* op = out + mat;
    #pragma unroll
    for (int i = 0; i < 32; i += 8)
        tile[y + i][x] = ip[(size_t)(by + y + i) * C + (bx + x)];
    __syncthreads();
    #pragma unroll
    for (int i = 0; i < 32; i += 8)
        op[(size_t)(bx + y + i) * R + (by + x)] = f2bf(tile[x][y + i]);
}

// ---------------- kernel 3: fused fp32 routing (unchanged, verified) ----------------
__global__ __launch_bounds__(256) void k_route(
    const float* __restrict__ h, const float* __restrict__ tok_emb,
    const float* __restrict__ ln_g, const float* __restrict__ ln_b,
    const float* __restrict__ Wg, const float* __restrict__ bg,
    const float* __restrict__ Wf, const float* __restrict__ bfv,
    const float* __restrict__ Wr, const float* __restrict__ br,
    const float* __restrict__ mu_g, const float* __restrict__ rs_g,
    float* __restrict__ tprob, int* __restrict__ list, int* __restrict__ cnt,
    float* __restrict__ imp_part)
{
    __shared__ __align__(16) char smem[62208];
    float* lgs  = (float*)(smem);                      // [1024]
    float* lbs  = (float*)(smem + 4096);               // [1024]
    float (*hsT)[64]  = (float(*)[64])(smem + 8192);   // [64 k][64 tok]
    float (*wgs)[32]  = (float(*)[32])(smem + 24576);  // [64 k][32 c]
    float (*gacc)[32] = (float(*)[32])(smem + 32768);  // [64 tok][32 c]
    float* mus = (float*)(smem + 40960);               // [64]
    float* rss = (float*)(smem + 41216);               // [64]
    float (*wrs)[4]     = (float(*)[4])(smem + 41472); // [64][4]
    float (*logit_s)[5] = (float(*)[5])(smem + 42496);
    float (*prob_s)[5]  = (float(*)[5])(smem + 43776);
    int* lcnt  = (int*)(smem + 45056);
    int* lbase = (int*)(smem + 45072);
    float (*agT)[64] = (float(*)[64])(smem);           // [64 j][64 tok]
    float (*wfs)[64] = (float(*)[64])(smem + 16384);   // [64 k][64 f]
    float (*uT)[64]  = (float(*)[64])(smem + 45824);   // [64 f][64 tok]

    int tid = threadIdx.x;
    int t0 = blockIdx.x * 64;

    ((float4*)lgs)[tid] = ((const float4*)ln_g)[tid];
    ((float4*)lbs)[tid] = ((const float4*)ln_b)[tid];
    if (tid < 64){ mus[tid] = mu_g[t0 + tid]; rss[tid] = rs_g[t0 + tid]; }
    if (tid < 64) ((float4*)wrs)[tid] = ((const float4*)Wr)[tid];
    if (tid < 4) lcnt[tid] = 0;
    __syncthreads();

    int l = tid & 63, w = tid >> 6;
    int tg = l & 7, cg = l >> 3, q = w;
    float g_[8][4];
    #pragma unroll
    for (int i=0;i<8;++i){ g_[i][0]=0.f; g_[i][1]=0.f; g_[i][2]=0.f; g_[i][3]=0.f; }
    int tokrow = tid >> 2;
    float m_ = mus[tokrow], r_ = rss[tokrow];
    const float* hrow = h + (size_t)(t0 + tokrow) * HDIM;

    for (int k0 = 0; k0 < HDIM; k0 += 64){
        #pragma unroll
        for (int p = 0; p < 4; ++p){
            int f4 = (tid & 3) + 4 * p;
            float4 v = ((const float4*)(hrow + k0))[f4];
            int c = f4 * 4;
            hsT[c+0][tokrow] = (v.x - m_) * r_ * lgs[k0+c+0] + lbs[k0+c+0];
            hsT[c+1][tokrow] = (v.y - m_) * r_ * lgs[k0+c+1] + lbs[k0+c+1];
            hsT[c+2][tokrow] = (v.z - m_) * r_ * lgs[k0+c+2] + lbs[k0+c+2];
            hsT[c+3][tokrow] = (v.w - m_) * r_ * lgs[k0+c+3] + lbs[k0+c+3];
        }
        {
            int wgrow = tid >> 2;
            #pragma unroll
            for (int p = 0; p < 2; ++p){
                int f4 = (tid & 3) + 4 * p;
                ((float4*)wgs[wgrow])[f4] = ((const float4*)(Wg + (size_t)(k0 + wgrow) * DGZ))[f4];
            }
        }
        __syncthreads();
        #pragma unroll
        for (int kk16 = 0; kk16 < 16; ++kk16){
            int kk = q * 16 + kk16;
            float4 a0 = ((float4*)hsT[kk])[tg*2];
            float4 a1 = ((float4*)hsT[kk])[tg*2+1];
            float4 wv = ((float4*)wgs[kk])[cg];
            float av[8] = {a0.x,a0.y,a0.z,a0.w,a1.x,a1.y,a1.z,a1.w};
            float wj[4] = {wv.x,wv.y,wv.z,wv.w};
            #pragma unroll
            for (int i=0;i<8;++i){
                g_[i][0] += av[i]*wj[0]; g_[i][1] += av[i]*wj[1];
                g_[i][2] += av[i]*wj[2]; g_[i][3] += av[i]*wj[3];
            }
        }
        __syncthreads();
    }
    for (int qq = 0; qq < 4; ++qq){
        if (w == qq){
            #pragma unroll
            for (int i=0;i<8;++i){
                int tok = tg*8+i;
                #pragma unroll
                for (int j=0;j<4;++j){
                    int c = cg*4+j;
                    if (qq == 0) gacc[tok][c] = g_[i][j];
                    else gacc[tok][c] += g_[i][j];
                }
            }
        }
        __syncthreads();
    }
    {
        int tokr = tid >> 2;
        #pragma unroll
        for (int p = 0; p < 2; ++p){
            int f4 = (tid & 3) + 4*p;
            float4 v = ((const float4*)(tok_emb + (size_t)(t0 + tokr) * DSZ))[f4];
            int j = f4 * 4;
            agT[j+0][tokr] = v.x; agT[j+1][tokr] = v.y;
            agT[j+2][tokr] = v.z; agT[j+3][tokr] = v.w;
        }
        int c = tid & 31, tok8 = (tid >> 5) * 8;
        float bgc = bg[c];
        #pragma unroll
        for (int i=0;i<8;++i){
            int tok = tok8 + i;
            agT[32 + c][tok] = gelu_f(gacc[tok][c] + bgc);
        }
        int row = tid >> 2;
        #pragma unroll
        for (int p = 0; p < 4; ++p){
            int f4 = (tid & 3) + 4*p;
            ((float4*)wfs[row])[f4] = ((const float4*)(Wf + (size_t)row * FMZ))[f4];
        }
    }
    __syncthreads();
    {
        int tok = tid & 63, fq = tid >> 6;
        float u_[16];
        #pragma unroll
        for (int i=0;i<16;++i) u_[i]=0.f;
        for (int j = 0; j < 64; ++j){
            float a = agT[j][tok];
            float wv[16];
            *(float4*)&wv[0]  = ((float4*)wfs[j])[fq*4+0];
            *(float4*)&wv[4]  = ((float4*)wfs[j])[fq*4+1];
            *(float4*)&wv[8]  = ((float4*)wfs[j])[fq*4+2];
            *(float4*)&wv[12] = ((float4*)wfs[j])[fq*4+3];
            #pragma unroll
            for (int i=0;i<16;++i) u_[i] += a * wv[i];
        }
        #pragma unroll
        for (int i=0;i<16;++i){
            int f = fq*16+i;
            uT[f][tok] = gelu_f(u_[i] + bfv[f]);
        }
    }
    __syncthreads();
    {
        int tok = tid & 63, e = tid >> 6;
        float lt = 0.f;
        #pragma unroll 8
        for (int f = 0; f < 64; ++f) lt += uT[f][tok] * wrs[f][e];
        logit_s[tok][e] = lt + br[e];
    }
    __syncthreads();
    int my_e = 0, my_pos = 0;
    if (tid < 64){
        int tok = tid;
        float l0 = logit_s[tok][0], l1 = logit_s[tok][1];
        float l2 = logit_s[tok][2], l3 = logit_s[tok][3];
        float mx = fmaxf(fmaxf(l0,l1), fmaxf(l2,l3));
        float p0 = expf(l0-mx), p1 = expf(l1-mx), p2 = expf(l2-mx), p3 = expf(l3-mx);
        float inv = 1.0f / (p0+p1+p2+p3);
        int be = 0; float bp = p0;
        if (p1 > bp){ bp = p1; be = 1; }
        if (p2 > bp){ bp = p2; be = 2; }
        if (p3 > bp){ bp = p3; be = 3; }
        tprob[t0 + tok] = bp * inv;
        prob_s[tok][0] = p0*inv; prob_s[tok][1] = p1*inv;
        prob_s[tok][2] = p2*inv; prob_s[tok][3] = p3*inv;
        my_e = be;
        my_pos = atomicAdd(&lcnt[be], 1);
    }
    __syncthreads();
    if (tid < 4) lbase[tid] = atomicAdd(&cnt[tid], lcnt[tid]);
    __syncthreads();
    if (tid < 64) list[my_e * NTOK + lbase[my_e] + my_pos] = t0 + tid;
    if (tid < 4){
        float s = 0.f;
        for (int t = 0; t < 64; ++t) s += prob_s[t][tid];
        imp_part[blockIdx.x * 4 + tid] = s;
    }
}

// ---------------- grouped expert GEMM: 256x256 tile, 8-phase counted-vmcnt ----------------
// 512 threads = 8 waves (2M x 4N). BK=64 split into two 32-k halves.
// LDS 128KiB: A: [2 dbuf][2 khalf][256 rows][32 k], B same at +64KiB.
// Loop body = 2 K-tiles (8 phases) with COMPILE-TIME buffer offsets (DOF 0/32768)
// so all ds_reads use loop-invariant base + immediate offset (no runtime dof VALU).
// No sched_barrier pinning (m141 lesson) — compiler schedules within phases.
// vmcnt(8) only at phases 1/3/5/7 ends (counted, never 0 in-loop, T4).
template<int KTD, int NT, bool PH1>
__global__ __launch_bounds__(512, 2) void k_gemm256(
    const unsigned short* __restrict__ Abase,
    const unsigned short* __restrict__ Bbase,
    const int* __restrict__ list, const int* __restrict__ cnt_g,
    const float* __restrict__ bias,
    unsigned short* __restrict__ A1out,
    const float* __restrict__ hres,
    const float* __restrict__ tprob,
    float* __restrict__ outp)
{
    constexpr int NKT = KTD / 64;
    constexpr int NKTm1 = NKT - 1;
    __shared__ __align__(16) char lds[131072];
    int e = blockIdx.z;
    int cnt = cnt_g[e];
    int m0 = blockIdx.y * 256;
    if (m0 >= cnt) return;
    int n0 = blockIdx.x * 256;
    int tid = threadIdx.x, w = tid >> 6, l = tid & 63;
    int wr = w >> 2, wc = w & 3;

    // staging mapping: thread -> (row = tid>>2 [+128 on 2nd load], src chunk jsrc)
    int srow = tid >> 2;
    int jsrc = (tid & 3) ^ ((tid >> 3) & 3);
    int g0 = m0 + srow;       if (g0 > cnt-1) g0 = cnt-1;
    int g1 = m0 + 128 + srow; if (g1 > cnt-1) g1 = cnt-1;
    int tok0 = list[e * NTOK + g0], tok1 = list[e * NTOK + g1];
    const unsigned short* Asrc0 = Abase + (size_t)tok0 * KTD + jsrc * 8;
    const unsigned short* Asrc1 = Abase + (size_t)tok1 * KTD + jsrc * 8;
    const unsigned short* Bsrc0 = Bbase + ((size_t)e * NT + n0 + srow) * KTD + jsrc * 8;
    const unsigned short* Bsrc1 = Bsrc0 + (size_t)128 * KTD;

    // fragment read offsets (swizzled: chunk = (l>>4) ^ (((l&15)>>1)&3), 2-way banks)
    int lane_off = (l & 15) * 64 + (((l >> 4) ^ (((l & 15) >> 1) & 3)) * 16);
    char* abase = lds + wr * 8192 + lane_off;            // + DOF + KCB + mh*4096 + m*1024
    char* bbase = lds + 65536 + wc * 4096 + lane_off;    // + DOF + KCB + n*1024

#define STAGE_A(KIDX, KC, DOF) do { \
    int kq_ = (KIDX); if (kq_ > NKTm1) kq_ = NKTm1; \
    size_t so_ = (size_t)kq_ * 64 + (KC) * 32; \
    gld_lds16(Asrc0 + so_, lds + (DOF) + (KC) * 16384 + tid * 16); \
    gld_lds16(Asrc1 + so_, lds + (DOF) + (KC) * 16384 + 8192 + tid * 16); } while(0)
#define STAGE_B(KIDX, KC, DOF) do { \
    int kq_ = (KIDX); if (kq_ > NKTm1) kq_ = NKTm1; \
    size_t so_ = (size_t)kq_ * 64 + (KC) * 32; \
    gld_lds16(Bsrc0 + so_, lds + 65536 + (DOF) + (KC) * 16384 + tid * 16); \
    gld_lds16(Bsrc1 + so_, lds + 65536 + (DOF) + (KC) * 16384 + 8192 + tid * 16); } while(0)
#define AFRAG(DOF, KCB, MH, M) (*(const bf16x8*)(abase + (DOF) + (KCB) + (MH) * 4096 + (M) * 1024))
#define BFRAG(DOF, KCB, N)     (*(const bf16x8*)(bbase + (DOF) + (KCB) + (N) * 1024))
#define MM16(MB, A0, A1, A2, A3) do { \
    acc[(MB)+0][0] = __builtin_amdgcn_mfma_f32_16x16x32_bf16(A0, b0, acc[(MB)+0][0], 0,0,0); \
    acc[(MB)+1][0] = __builtin_amdgcn_mfma_f32_16x16x32_bf16(A1, b0, acc[(MB)+1][0], 0,0,0); \
    acc[(MB)+2][0] = __builtin_amdgcn_mfma_f32_16x16x32_bf16(A2, b0, acc[(MB)+2][0], 0,0,0); \
    acc[(MB)+3][0] = __builtin_amdgcn_mfma_f32_16x16x32_bf16(A3, b0, acc[(MB)+3][0], 0,0,0); \
    acc[(MB)+0][1] = __builtin_amdgcn_mfma_f32_16x16x32_bf16(A0, b1, acc[(MB)+0][1], 0,0,0); \
    acc[(MB)+1][1] = __builtin_amdgcn_mfma_f32_16x16x32_bf16(A1, b1, acc[(MB)+1][1], 0,0,0); \
    acc[(MB)+2][1] = __builtin_amdgcn_mfma_f32_16x16x32_bf16(A2, b1, acc[(MB)+2][1], 0,0,0); \
    acc[(MB)+3][1] = __builtin_amdgcn_mfma_f32_16x16x32_bf16(A3, b1, acc[(MB)+3][1], 0,0,0); \
    acc[(MB)+0][2] = __builtin_amdgcn_mfma_f32_16x16x32_bf16(A0, b2, acc[(MB)+0][2], 0,0,0); \
    acc[(MB)+1][2] = __builtin_amdgcn_mfma_f32_16x16x32_bf16(A1, b2, acc[(MB)+1][2], 0,0,0); \
    acc[(MB)+2][2] = __builtin_amdgcn_mfma_f32_16x16x32_bf16(A2, b2, acc[(MB)+2][2], 0,0,0); \
    acc[(MB)+3][2] = __builtin_amdgcn_mfma_f32_16x16x32_bf16(A3, b2, acc[(MB)+3][2], 0,0,0); \
    acc[(MB)+0][3] = __builtin_amdgcn_mfma_f32_16x16x32_bf16(A0, b3, acc[(MB)+0][3], 0,0,0); \
    acc[(MB)+1][3] = __builtin_amdgcn_mfma_f32_16x16x32_bf16(A1, b3, acc[(MB)+1][3], 0,0,0); \
    acc[(MB)+2][3] = __builtin_amdgcn_mfma_f32_16x16x32_bf16(A2, b3, acc[(MB)+2][3], 0,0,0); \
    acc[(MB)+3][3] = __builtin_amdgcn_mfma_f32_16x16x32_bf16(A3, b3, acc[(MB)+3][3], 0,0,0); } while(0)

// PH_AB: loads A mh0 + B fragments of (DOF,KCB), stages one A half-tile, MFMA quadrant 0
#define PH_AB(DOF, KCB, SK, SKC, SDOF) do { \
    bf16x8 a0 = AFRAG(DOF,KCB,0,0), a1 = AFRAG(DOF,KCB,0,1), a2 = AFRAG(DOF,KCB,0,2), a3 = AFRAG(DOF,KCB,0,3); \
    b0 = BFRAG(DOF,KCB,0); b1 = BFRAG(DOF,KCB,1); b2 = BFRAG(DOF,KCB,2); b3 = BFRAG(DOF,KCB,3); \
    STAGE_A(SK, SKC, SDOF); \
    __builtin_amdgcn_s_barrier(); \
    __builtin_amdgcn_s_setprio(1); \
    MM16(0, a0, a1, a2, a3); \
    __builtin_amdgcn_s_setprio(0); \
    asm volatile("s_waitcnt lgkmcnt(0)" ::: "memory"); \
    __builtin_amdgcn_s_barrier(); } while(0)
// PH_A: loads A mh1 fragments (reuses b0..b3), stages one B half-tile, MFMA quadrant 1,
//       counted vmcnt(8) fence (4 half-tiles stay in flight)
#define PH_A(DOF, KCB, SK, SKC, SDOF) do { \
    bf16x8 a0 = AFRAG(DOF,KCB,1,0), a1 = AFRAG(DOF,KCB,1,1), a2 = AFRAG(DOF,KCB,1,2), a3 = AFRAG(DOF,KCB,1,3); \
    STAGE_B(SK, SKC, SDOF); \
    __builtin_amdgcn_s_barrier(); \
    __builtin_amdgcn_s_setprio(1); \
    MM16(4, a0, a1, a2, a3); \
    __builtin_amdgcn_s_setprio(0); \
    asm volatile("s_waitcnt vmcnt(8) lgkmcnt(0)" ::: "memory"); \
    __builtin_amdgcn_s_barrier(); } while(0)

    f32x4 acc[8][4] = {};
    bf16x8 b0, b1, b2, b3;

    // prologue: stage (0,kc0,D0),(0,kc1,D0),(1,kc0,D1); retire (0,kc0) -> 8 in flight
    STAGE_A(0, 0, 0);     STAGE_B(0, 0, 0);
    STAGE_A(0, 1, 0);     STAGE_B(0, 1, 0);
    STAGE_A(1, 0, 32768); STAGE_B(1, 0, 32768);
    asm volatile("s_waitcnt vmcnt(8)" ::: "memory");
    __builtin_amdgcn_s_barrier();

    #pragma unroll 1
    for (int kt = 0; kt < NKT; kt += 2){
        // K-tile kt (buffer 0)
        PH_AB(0,     0,     kt+1, 1, 32768);
        PH_A (0,     0,     kt+1, 1, 32768);
        PH_AB(0,     16384, kt+2, 0, 0);
        PH_A (0,     16384, kt+2, 0, 0);
        // K-tile kt+1 (buffer 32768)
        PH_AB(32768, 0,     kt+2, 1, 0);
        PH_A (32768, 0,     kt+2, 1, 0);
        PH_AB(32768, 16384, kt+3, 0, 32768);
        PH_A (32768, 16384, kt+3, 0, 32768);
    }

    // epilogue: C/D layout col = lane&15 (+16*n), row = (lane>>4)*4 + reg (+16*M)
    float bs[4];
    #pragma unroll
    for (int n = 0; n < 4; ++n)
        bs[n] = bias[e * NT + n0 + wc * 64 + n * 16 + (l & 15)];
    #pragma unroll
    for (int M = 0; M < 8; ++M){
        #pragma unroll
        for (int r = 0; r < 4; ++r){
            int row = wr * 128 + M * 16 + (l >> 4) * 4 + r;
            int g = m0 + row;
            if (g < cnt){
                int tok = list[e * NTOK + g];
                if (PH1){
                    #pragma unroll
                    for (int n = 0; n < 4; ++n){
                        int col = n0 + wc * 64 + n * 16 + (l & 15);
                        float v = acc[M][n][r] + bs[n];
                        A1out[(size_t)tok * FFZ + col] = f2bf(gelu_f(v));
                    }
                } else {
                    float sc = 0.5f * tprob[tok];
                    #pragma unroll
                    for (int n = 0; n < 4; ++n){
                        int col = n0 + wc * 64 + n * 16 + (l & 15);
                        float v = acc[M][n][r] + bs[n];
                        size_t o = (size_t)tok * HDIM + col;
                        outp[o] = hres[o] + sc * v;
                    }
                }
            }
        }
    }
#undef STAGE_A
#undef STAGE_B
#undef AFRAG
#undef BFRAG
#undef MM16
#undef PH_AB
#undef PH_A
}

// ---------------- final: lb_loss ----------------
__global__ void k_final(const float* __restrict__ imp_part, const int* __restrict__ cnt,
                        float* __restrict__ outp){
    __shared__ float imp_s[4];
    int tid = threadIdx.x;
    if (tid < 4){
        float s = 0.f;
        for (int b = 0; b < 256; ++b) s += imp_part[b*4 + tid];
        imp_s[tid] = s;
    }
    __syncthreads();
    if (tid == 0){
        float lb = 0.f;
        #pragma unroll
        for (int e = 0; e < 4; ++e) lb += imp_s[e] * (float)cnt[e];
        outp[(size_t)NTOK * HDIM] = (float)NEXP * lb / ((float)NTOK * (float)NTOK + 1e-8f);
    }
}

extern "C" void kernel_launch(void* const* d_in, const int* in_sizes, int n_in,
                              void* d_out, int out_size, void* d_ws, size_t ws_size,
                              hipStream_t stream){
    const float* h       = (const float*)d_in[0];
    const float* tok_emb = (const float*)d_in[1];
    const float* ln_g = (const float*)d_in[3];
    const float* ln_b = (const float*)d_in[4];
    const float* Wg   = (const float*)d_in[5];
    const float* bg   = (const float*)d_in[6];
    const float* Wf   = (const float*)d_in[7];
    const float* bfv  = (const float*)d_in[8];
    const float* Wr   = (const float*)d_in[9];
    const float* br   = (const float*)d_in[10];
    const float* W1   = (const float*)d_in[11];
    const float* b1   = (const float*)d_in[12];
    const float* W2   = (const float*)d_in[13];
    const float* b2   = (const float*)d_in[14];
    float* outp = (float*)d_out;
    char* ws = (char*)d_ws;

    unsigned short* h_bf = (unsigned short*)(ws);               // 33554432 B
    unsigned short* W1T  = (unsigned short*)(ws + 33554432);    // 16777216 B  [E][FFZ][HDIM]
    unsigned short* W2T  = (unsigned short*)(ws + 50331648);    // 16777216 B  [E][HDIM][FFZ]
    unsigned short* A1   = (unsigned short*)(ws + 67108864);    // 67108864 B  [NTOK][FFZ]
    float* mu_g  = (float*)(ws + 134217728);
    float* rs_g  = (float*)(ws + 134283264);
    float* tprob = (float*)(ws + 134348800);
    int*   list  = (int*)(ws + 134414336);                      // [E][NTOK]
    int*   cnt   = (int*)(ws + 134676480);                      // [E]
    float* imp   = (float*)(ws + 134676736);                    // [256][E]

    hipMemsetAsync(cnt, 0, NEXP * sizeof(int), stream);
    k_stats<<<NTOK/4, 256, 0, stream>>>(h, h_bf, mu_g, rs_g);
    k_transpose_bf<<<dim3(FFZ/32, HDIM/32, NEXP), dim3(32,8), 0, stream>>>(W1, W1T, HDIM, FFZ);
    k_transpose_bf<<<dim3(HDIM/32, FFZ/32, NEXP), dim3(32,8), 0, stream>>>(W2, W2T, FFZ, HDIM);
    k_route<<<NTOK/64, 256, 0, stream>>>(h, tok_emb, ln_g, ln_b, Wg, bg, Wf, bfv, Wr, br,
                                         mu_g, rs_g, tprob, list, cnt, imp);
    k_gemm256<HDIM, FFZ, true><<<dim3(FFZ/256, NTOK/256, NEXP), 512, 0, stream>>>(
        h_bf, W1T, list, cnt, b1, A1, nullptr, nullptr, nullptr);
    k_gemm256<FFZ, HDIM, false><<<dim3(HDIM/256, NTOK/256, NEXP), 512, 0, stream>>>(
        A1, W2T, list, cnt, b2, nullptr, h, tprob, outp);
    k_final<<<1, 64, 0, stream>>>(imp, cnt, outp);
}